// Round 2
// baseline (65.364 us; speedup 1.0000x reference)
//
#include <hip/hip_runtime.h>

#define NPTS 256
#define NGRIDS 1024
#define KCUBE 343
#define EPSF 1e-4f
#define OUT_OF_REACH 1.0f

// One block per point. Phase 1: compact active grids (gw > 0) into LDS.
// Phase 2: waves cooperatively interpolate the 7^3 nodes of each active grid.
__global__ __launch_bounds__(256) void mosaic_sdf_kernel(
    const float* __restrict__ points,    // (256,3)
    const float* __restrict__ centers,   // (1024,3)
    const float* __restrict__ scales,    // (1024,)
    const float* __restrict__ sdf,       // (1024,7,7,7)
    float* __restrict__ out)             // (256,)
{
    const int p    = blockIdx.x;
    const int tid  = threadIdx.x;
    const int wid  = tid >> 6;
    const int lane = tid & 63;

    __shared__ int   s_count;
    __shared__ int   s_g [NGRIDS];
    __shared__ float s_ax[NGRIDS];
    __shared__ float s_ay[NGRIDS];
    __shared__ float s_az[NGRIDS];
    __shared__ float s_gw[NGRIDS];
    __shared__ float s_red[8];

    if (tid == 0) s_count = 0;
    __syncthreads();

    const float px = points[3 * p + 0];
    const float py = points[3 * p + 1];
    const float pz = points[3 * p + 2];

    // ---------- Phase 1: grid-level weights + compaction ----------
    float den = 0.0f;
    for (int g = tid; g < NGRIDS; g += 256) {
        const float s  = scales[g];
        const float rx = (px - centers[3 * g + 0]) / s;
        const float ry = (py - centers[3 * g + 1]) / s;
        const float rz = (pz - centers[3 * g + 2]) / s;
        const float gd = sqrtf(rx * rx + ry * ry + rz * rz);
        const float gw = 1.0f - gd + EPSF;
        if (gw > 0.0f) {
            const int e = atomicAdd(&s_count, 1);
            s_g [e] = g;
            // d_axis,i = rel*3 + 3 - i  (coord_step = 2/6)
            s_ax[e] = rx * 3.0f + 3.0f;
            s_ay[e] = ry * 3.0f + 3.0f;
            s_az[e] = rz * 3.0f + 3.0f;
            s_gw[e] = gw;
            den += gw;
        }
    }
    __syncthreads();

    // ---------- Phase 2: kernel interpolation per active grid ----------
    const int count = s_count;
    float num = 0.0f;
    for (int e = wid; e < count; e += 4) {
        const float ax = s_ax[e];
        const float ay = s_ay[e];
        const float az = s_az[e];
        const float* __restrict__ sg = sdf + s_g[e] * KCUBE;

        float wsum = 0.0f, raw = 0.0f;
        #pragma unroll
        for (int it = 0; it < 6; ++it) {
            const int n = lane + it * 64;
            if (n < KCUBE) {
                const int i = n / 49;
                const int r = n - i * 49;
                const int j = r / 7;
                const int l = r - j * 7;
                const float dx = ax - (float)i;
                const float dy = ay - (float)j;
                const float dz = az - (float)l;
                const float d2   = fmaf(dx, dx, fmaf(dy, dy, dz * dz));
                const float dist = sqrtf(d2);
                const float w    = (dist <= 1.0f) ? (1.0f - dist) : 0.0f;
                wsum += w;
                raw   = fmaf(w, sg[n], raw);
            }
        }
        // wave64 reduction
        #pragma unroll
        for (int off = 32; off; off >>= 1) {
            wsum += __shfl_down(wsum, off);
            raw  += __shfl_down(raw,  off);
        }
        if (lane == 0) {
            const float interp = (wsum > EPSF) ? (raw / wsum) : 0.0f;
            num = fmaf(interp, s_gw[e], num);
        }
    }

    // ---------- Block reduction of num / den ----------
    #pragma unroll
    for (int off = 32; off; off >>= 1) den += __shfl_down(den, off);
    #pragma unroll
    for (int off = 32; off; off >>= 1) num += __shfl_down(num, off);
    if (lane == 0) {
        s_red[wid]     = den;
        s_red[4 + wid] = num;
    }
    __syncthreads();

    if (tid == 0) {
        const float dtot = s_red[0] + s_red[1] + s_red[2] + s_red[3];
        const float ntot = s_red[4] + s_red[5] + s_red[6] + s_red[7];
        float v;
        if (dtot < EPSF)      v = OUT_OF_REACH;   // uncovered
        else if (dtot > EPSF) v = ntot / dtot;
        else                  v = 0.0f;           // gsum == EPS exactly: weights zeroed
        out[p] = v;
    }
}

extern "C" void kernel_launch(void* const* d_in, const int* in_sizes, int n_in,
                              void* d_out, int out_size, void* d_ws, size_t ws_size,
                              hipStream_t stream) {
    const float* points  = (const float*)d_in[0];
    const float* centers = (const float*)d_in[1];
    const float* scales  = (const float*)d_in[2];
    const float* sdf     = (const float*)d_in[3];
    float* out = (float*)d_out;

    mosaic_sdf_kernel<<<NPTS, 256, 0, stream>>>(points, centers, scales, sdf, out);
}

// Round 6
// 62.169 us; speedup vs baseline: 1.0514x; 1.0514x over previous
//
#include <hip/hip_runtime.h>

#define NPTS 256
#define NGRIDS 1024
#define KCUBE 343
#define EPSF 1e-4f
#define OUT_OF_REACH 1.0f

// One block per point, 1024 threads (16 waves/CU).
// Phase 1: one grid per thread, compact active grids (gw > 0) into LDS.
// Phase 2: each wave interpolates the 7^3 nodes of one active grid.
__global__ __launch_bounds__(1024) void mosaic_sdf_kernel(
    const float* __restrict__ points,    // (256,3)
    const float* __restrict__ centers,   // (1024,3)
    const float* __restrict__ scales,    // (1024,)
    const float* __restrict__ sdf,       // (1024,7,7,7)
    float* __restrict__ out)             // (256,)
{
    const int p    = blockIdx.x;
    const int tid  = threadIdx.x;
    const int wid  = tid >> 6;   // 0..15
    const int lane = tid & 63;

    __shared__ int   s_count;
    __shared__ int   s_g [NGRIDS];
    __shared__ float s_ax[NGRIDS];
    __shared__ float s_ay[NGRIDS];
    __shared__ float s_az[NGRIDS];
    __shared__ float s_gw[NGRIDS];
    __shared__ float s_redD[16];
    __shared__ float s_redN[16];

    if (tid == 0) s_count = 0;
    __syncthreads();

    const float px = points[3 * p + 0];
    const float py = points[3 * p + 1];
    const float pz = points[3 * p + 2];

    // ---------- Phase 1: grid weights + compaction (1 grid/thread) ----------
    {
        const int   g  = tid;                       // 1024 threads == 1024 grids
        const float rs = 1.0f / scales[g];          // 1 divide instead of 3
        const float rx = (px - centers[3 * g + 0]) * rs;
        const float ry = (py - centers[3 * g + 1]) * rs;
        const float rz = (pz - centers[3 * g + 2]) * rs;
        const float gd = sqrtf(fmaf(rx, rx, fmaf(ry, ry, rz * rz)));
        const float gw = 1.0f - gd + EPSF;
        float den = 0.0f;
        if (gw > 0.0f) {
            den = gw;
            const int e = atomicAdd(&s_count, 1);
            s_g [e] = g;
            // d_axis,i = rel*3 + 3 - i   (coord_step = 2/6)
            s_ax[e] = fmaf(rx, 3.0f, 3.0f);
            s_ay[e] = fmaf(ry, 3.0f, 3.0f);
            s_az[e] = fmaf(rz, 3.0f, 3.0f);
            s_gw[e] = gw;
        }
        #pragma unroll
        for (int off = 32; off; off >>= 1) den += __shfl_down(den, off);
        if (lane == 0) s_redD[wid] = den;
    }
    __syncthreads();

    // ---------- Phase 2: node interpolation, one active grid per wave ----------
    const int count = s_count;
    float num = 0.0f;
    for (int e = wid; e < count; e += 16) {
        const float ax = s_ax[e];
        const float ay = s_ay[e];
        const float az = s_az[e];
        const float* __restrict__ sg = sdf + s_g[e] * KCUBE;

        float wsum = 0.0f, raw = 0.0f;
        #pragma unroll
        for (int it = 0; it < 6; ++it) {
            const int n = lane + it * 64;
            if (n < KCUBE) {
                const int i = n / 49;
                const int r = n - i * 49;
                const int j = r / 7;
                const int l = r - j * 7;
                const float dx = ax - (float)i;
                const float dy = ay - (float)j;
                const float dz = az - (float)l;
                const float d2   = fmaf(dx, dx, fmaf(dy, dy, dz * dz));
                const float dist = sqrtf(d2);
                const float w    = (dist <= 1.0f) ? (1.0f - dist) : 0.0f;
                wsum += w;
                raw   = fmaf(w, sg[n], raw);
            }
        }
        #pragma unroll
        for (int off = 32; off; off >>= 1) {
            wsum += __shfl_down(wsum, off);
            raw  += __shfl_down(raw,  off);
        }
        if (lane == 0) {
            const float interp = (wsum > EPSF) ? (raw / wsum) : 0.0f;
            num = fmaf(interp, s_gw[e], num);
        }
    }
    if (lane == 0) s_redN[wid] = num;
    __syncthreads();

    // ---------- Final reduction ----------
    if (tid == 0) {
        float dtot = 0.0f, ntot = 0.0f;
        #pragma unroll
        for (int i = 0; i < 16; ++i) { dtot += s_redD[i]; ntot += s_redN[i]; }
        float v;
        if (dtot < EPSF)      v = OUT_OF_REACH;   // uncovered
        else if (dtot > EPSF) v = ntot / dtot;
        else                  v = 0.0f;           // gsum == EPS exactly: weights zeroed
        out[p] = v;
    }
}

extern "C" void kernel_launch(void* const* d_in, const int* in_sizes, int n_in,
                              void* d_out, int out_size, void* d_ws, size_t ws_size,
                              hipStream_t stream) {
    const float* points  = (const float*)d_in[0];
    const float* centers = (const float*)d_in[1];
    const float* scales  = (const float*)d_in[2];
    const float* sdf     = (const float*)d_in[3];
    float* out = (float*)d_out;

    mosaic_sdf_kernel<<<NPTS, 1024, 0, stream>>>(points, centers, scales, sdf, out);
}

// Round 7
// 61.896 us; speedup vs baseline: 1.0560x; 1.0044x over previous
//
#include <hip/hip_runtime.h>

#define NPTS 256
#define NGRIDS 1024
#define KCUBE 343
#define EPSF 1e-4f
#define OUT_OF_REACH 1.0f

// One block per point, 1024 threads (16 waves/CU).
// Phase 1: one grid per thread, compact active grids (gw > 0) into LDS.
// Phase 2: each wave interpolates the 7^3 nodes of one active grid; lane 0
//          accumulates num/den via LDS float atomics (≈10 total, no contention).
__global__ __launch_bounds__(1024) void mosaic_sdf_kernel(
    const float* __restrict__ points,    // (256,3)
    const float* __restrict__ centers,   // (1024,3)
    const float* __restrict__ scales,    // (1024,)
    const float* __restrict__ sdf,       // (1024,7,7,7)
    float* __restrict__ out)             // (256,)
{
    const int p    = blockIdx.x;
    const int tid  = threadIdx.x;
    const int wid  = tid >> 6;   // 0..15
    const int lane = tid & 63;

    __shared__ int   s_count;
    __shared__ float s_den;
    __shared__ float s_num;
    __shared__ int   s_g [NGRIDS];
    __shared__ float s_ax[NGRIDS];
    __shared__ float s_ay[NGRIDS];
    __shared__ float s_az[NGRIDS];
    __shared__ float s_gw[NGRIDS];

    if (tid == 0) { s_count = 0; s_den = 0.0f; s_num = 0.0f; }
    __syncthreads();

    const float px = points[3 * p + 0];
    const float py = points[3 * p + 1];
    const float pz = points[3 * p + 2];

    // ---------- Phase 1: grid weights + compaction (1 grid/thread) ----------
    {
        const int   g  = tid;                       // 1024 threads == 1024 grids
        const float rs = 1.0f / scales[g];          // 1 divide instead of 3
        const float rx = (px - centers[3 * g + 0]) * rs;
        const float ry = (py - centers[3 * g + 1]) * rs;
        const float rz = (pz - centers[3 * g + 2]) * rs;
        const float gd = sqrtf(fmaf(rx, rx, fmaf(ry, ry, rz * rz)));
        const float gw = 1.0f - gd + EPSF;
        if (gw > 0.0f) {
            const int e = atomicAdd(&s_count, 1);
            s_g [e] = g;
            // d_axis,i = rel*3 + 3 - i   (coord_step = 2/6)
            s_ax[e] = fmaf(rx, 3.0f, 3.0f);
            s_ay[e] = fmaf(ry, 3.0f, 3.0f);
            s_az[e] = fmaf(rz, 3.0f, 3.0f);
            s_gw[e] = gw;
        }
    }
    __syncthreads();

    // ---------- Phase 2: node interpolation, one active grid per wave ----------
    const int count = s_count;
    for (int e = wid; e < count; e += 16) {
        const float ax = s_ax[e];
        const float ay = s_ay[e];
        const float az = s_az[e];
        const float* __restrict__ sg = sdf + s_g[e] * KCUBE;

        float wsum = 0.0f, raw = 0.0f;
        #pragma unroll
        for (int it = 0; it < 6; ++it) {
            const int n = lane + it * 64;
            if (n < KCUBE) {
                const int i = n / 49;
                const int r = n - i * 49;
                const int j = r / 7;
                const int l = r - j * 7;
                const float dx = ax - (float)i;
                const float dy = ay - (float)j;
                const float dz = az - (float)l;
                const float d2   = fmaf(dx, dx, fmaf(dy, dy, dz * dz));
                const float dist = sqrtf(d2);
                const float w    = (dist <= 1.0f) ? (1.0f - dist) : 0.0f;
                wsum += w;
                raw   = fmaf(w, sg[n], raw);
            }
        }
        #pragma unroll
        for (int off = 32; off; off >>= 1) {
            wsum += __shfl_down(wsum, off);
            raw  += __shfl_down(raw,  off);
        }
        if (lane == 0) {
            const float gw     = s_gw[e];
            const float interp = (wsum > EPSF) ? (raw / wsum) : 0.0f;
            atomicAdd(&s_num, interp * gw);
            atomicAdd(&s_den, gw);
        }
    }
    __syncthreads();

    // ---------- Epilogue ----------
    if (tid == 0) {
        const float dtot = s_den;
        const float ntot = s_num;
        float v;
        if (dtot < EPSF)      v = OUT_OF_REACH;   // uncovered
        else if (dtot > EPSF) v = ntot / dtot;
        else                  v = 0.0f;           // gsum == EPS exactly: weights zeroed
        out[p] = v;
    }
}

extern "C" void kernel_launch(void* const* d_in, const int* in_sizes, int n_in,
                              void* d_out, int out_size, void* d_ws, size_t ws_size,
                              hipStream_t stream) {
    const float* points  = (const float*)d_in[0];
    const float* centers = (const float*)d_in[1];
    const float* scales  = (const float*)d_in[2];
    const float* sdf     = (const float*)d_in[3];
    float* out = (float*)d_out;

    mosaic_sdf_kernel<<<NPTS, 1024, 0, stream>>>(points, centers, scales, sdf, out);
}